// Round 6
// baseline (64.094 us; speedup 1.0000x reference)
//
#include <hip/hip_runtime.h>
#include <hip/hip_bf16.h>
#include <stdint.h>

// Problem constants (fixed by setup_inputs): B=2, C=256, H=W=64, dg=4, K=3x3.
#define HW   4096
#define NB   2

typedef float f32x4 __attribute__((ext_vector_type(4)));
typedef short s16x8 __attribute__((ext_vector_type(8)));

__device__ __forceinline__ unsigned short f2bf(float f) {
    // round-to-nearest-even f32 -> bf16
    union { float f; unsigned int u; } v; v.f = f;
    unsigned int u = v.u;
    unsigned int r = (u + 0x7FFFu + ((u >> 16) & 1u)) >> 16;
    return (unsigned short)r;
}

__device__ __forceinline__ float bf2f(unsigned short u) {
    union { unsigned int u; float f; } v; v.u = ((unsigned int)u) << 16;
    return v.f;
}

__device__ __forceinline__ unsigned short f2h(float f) {
    union { _Float16 h; unsigned short u; } v; v.h = (_Float16)f; return v.u;
}

__device__ __forceinline__ float h2f(unsigned short u) {
    union { unsigned short u; _Float16 h; } v; v.u = u; return (float)v.h;
}

// ---------------------------------------------------------------------------
// K_prep: transpose + weight-fragment reorder (params moved into k_main).
//   blocks [0,1024)     : NCHW f32 -> NHWC bf16 transpose  (fbuf)
//   blocks [1024,1600)  : weights -> bf16 MFMA A-frag order (wfrag)
// ---------------------------------------------------------------------------
__global__ void __launch_bounds__(256)
k_prep(const float* __restrict__ regf, const float* __restrict__ clsf,
       const float* __restrict__ wr,   const float* __restrict__ wc,
       unsigned short* __restrict__ fbuf, unsigned short* __restrict__ wfrag) {
    int bb = blockIdx.x;
    if (bb < 1024) {
        // ---- NCHW f32 -> NHWC bf16 ----
        __shared__ float tile[64][65];
        int bid = bb;
        int pt = bid & 63;
        int cb = (bid >> 6) & 3;
        int b  = (bid >> 8) & 1;
        int cv = bid >> 9;
        const float* src = cv ? clsf : regf;
        int t = threadIdx.x;
        int pl = t & 63, q = t >> 6;
        #pragma unroll
        for (int i = 0; i < 16; ++i) {
            int cl = q + i * 4;
            tile[cl][pl] = src[((size_t)(b * 256 + cb * 64 + cl)) * HW + pt * 64 + pl];
        }
        __syncthreads();
        int cpair = t & 31, prow = t >> 5;
        #pragma unroll
        for (int i = 0; i < 8; ++i) {
            int p = i * 8 + prow;
            unsigned int u0 = f2bf(tile[cpair * 2][p]);
            unsigned int u1 = f2bf(tile[cpair * 2 + 1][p]);
            *(unsigned int*)&fbuf[((size_t)((cv * 2 + b) * HW + pt * 64 + p)) * 256
                                  + cb * 64 + cpair * 2] = u0 | (u1 << 16);
        }
    } else {
        // ---- weights -> A-frag: L = conv*73728 + ((s*2+kk)*16+ot)*64+lane ----
        int L = (bb - 1024) * 256 + threadIdx.x;
        int conv = L / 73728;
        int r = L - conv * 73728;
        int lane = r & 63;
        int ot = (r >> 6) & 15;
        int kk = (r >> 10) & 1;
        int s  = r >> 11;
        int k = s >> 2, g = s & 3;
        int o  = ot * 16 + (lane & 15);
        int cb = kk * 32 + (lane >> 4) * 8;
        const float* w = conv ? wc : wr;
        s16x8 v;
        #pragma unroll
        for (int j = 0; j < 8; ++j) {
            int c = cb + j;
            v[j] = (short)f2bf(w[((size_t)o * 256 + g * 64 + c) * 9 + k]);
        }
        *(s16x8*)(wfrag + (size_t)L * 8) = v;
    }
}

// ---------------------------------------------------------------------------
// K_main: fused implicit GEMM. Block = (conv,b,64-pixel tile) x 256 Cout.
// 256 blocks x 512 threads (8 waves, 1 block/CU). Wave wv: 32 Cout x 64 px.
// Prologue: block computes its own bilinear params (offset 1x1 conv) into LDS
// (packed 4xf16 weights + 4xu16 row idx = 16B per (s,px)).
// Loop: gathers(s+1)+par(s+2) issued before a raw s_barrier (lgkmcnt-only
// drain, vmcnt stays in flight); A-frags register-double-buffered; MFMA(s);
// loadA(s+1); lerp + v_cvt_pk_bf16_f32 pack + vt write (s+1).
// ---------------------------------------------------------------------------
__global__ void __launch_bounds__(512, 2)
k_main(const float* __restrict__ pred, const float* __restrict__ woff,
       const unsigned short* __restrict__ fbuf, const unsigned short* __restrict__ wfrag,
       float* __restrict__ out) {
    __shared__ __align__(16) unsigned short vt[2][64][72];     // 18432 B
    __shared__ __align__(16) unsigned short par_lds[36][64][8]; // 36864 B

    int bid0 = blockIdx.x;
    int bid = (bid0 & 7) * 32 + (bid0 >> 3);       // XCD-contiguous swizzle (256%8==0)
    int conv = bid >> 7;
    int b    = (bid >> 6) & 1;
    int pt   = bid & 63;                           // tile row: h = pt, w = lane
    int p0   = pt * 64;

    int tid  = threadIdx.x;
    int lane = tid & 63;
    int wv   = tid >> 6;                           // wave id = Cout group (8 x 32)
    int px   = tid >> 3;                           // build: pixel 0..63
    int cg   = tid & 7;                            // build: channel granule (8 ch)

    const char* fbb = (const char*)(fbuf + (size_t)(conv * 2 + b) * HW * 256);
    const unsigned short* wfc = wfrag + (size_t)conv * 73728 * 8;

    // ---- prologue: params for this block's 64 pixels x 36 (k,g) sets ----
    {
        int j   = wv;                              // set-group: s = j + t*8
        int lpx = lane;                            // pixel within tile (w = lpx)
        const float* pb = pred + (size_t)b * 34 * HW + p0 + lpx;
        float oyA[5], oxA[5];
        #pragma unroll
        for (int t = 0; t < 5; ++t) { oyA[t] = 0.f; oxA[t] = 0.f; }
        for (int c = 0; c < 34; ++c) {
            float pv = pb[c * HW];
            #pragma unroll
            for (int t = 0; t < 5; ++t) {
                int s = j + t * 8;
                if (s < 36) {
                    int k = s >> 2, g = s & 3;
                    int row = ((g * 9 + k) * 2) * 34;
                    oyA[t] += woff[row + c]      * pv;
                    oxA[t] += woff[row + 34 + c] * pv;
                }
            }
        }
        #pragma unroll
        for (int t = 0; t < 5; ++t) {
            int s = j + t * 8;
            if (s < 36) {
                int k = s >> 2;
                int ky = k / 3, kx = k - ky * 3;
                float py = oyA[t] + (float)(pt  + ky - 1);
                float pxf = oxA[t] + (float)(lpx + kx - 1);
                float fy0 = floorf(py), fx0 = floorf(pxf);
                int y0 = (int)fy0, x0 = (int)fx0;
                float fy = py - fy0, fx = pxf - fx0;
                float wy0 = 1.f - fy, wy1 = fy, wx0 = 1.f - fx, wx1 = fx;
                if (!(y0 >= 0  && y0 <= 63)) wy0 = 0.f;
                if (!(y0 >= -1 && y0 <= 62)) wy1 = 0.f;
                if (!(x0 >= 0  && x0 <= 63)) wx0 = 0.f;
                if (!(x0 >= -1 && x0 <= 62)) wx1 = 0.f;
                int cy0 = min(max(y0, 0), 63),     cy1 = min(max(y0 + 1, 0), 63);
                int cx0 = min(max(x0, 0), 63),     cx1 = min(max(x0 + 1, 0), 63);
                s16x8 pk;
                pk[0] = (short)f2h(wy0 * wx0);
                pk[1] = (short)f2h(wy0 * wx1);
                pk[2] = (short)f2h(wy1 * wx0);
                pk[3] = (short)f2h(wy1 * wx1);
                pk[4] = (short)(unsigned short)(cy0 * 64 + cx0);
                pk[5] = (short)(unsigned short)(cy0 * 64 + cx1);
                pk[6] = (short)(unsigned short)(cy1 * 64 + cx0);
                pk[7] = (short)(unsigned short)(cy1 * 64 + cx1);
                *(s16x8*)&par_lds[s][lpx][0] = pk;
            }
        }
    }
    __syncthreads();

    f32x4 acc[2][4];
    #pragma unroll
    for (int i = 0; i < 2; ++i)
        #pragma unroll
        for (int j = 0; j < 4; ++j)
            acc[i][j] = (f32x4){0.f, 0.f, 0.f, 0.f};

    struct Par { float w0, w1, w2, w3; int o0, o1, o2, o3; };
    struct Gat { s16x8 a, b, c, d; };

    auto ldpar = [&](int s) -> Par {
        s16x8 raw = *(const s16x8*)&par_lds[s][px][0];   // 8 lanes broadcast
        Par P;
        P.w0 = h2f((unsigned short)raw[0]);
        P.w1 = h2f((unsigned short)raw[1]);
        P.w2 = h2f((unsigned short)raw[2]);
        P.w3 = h2f((unsigned short)raw[3]);
        P.o0 = ((int)(unsigned short)raw[4]) << 9;       // row * 512 B (bf16 NHWC)
        P.o1 = ((int)(unsigned short)raw[5]) << 9;
        P.o2 = ((int)(unsigned short)raw[6]) << 9;
        P.o3 = ((int)(unsigned short)raw[7]) << 9;
        return P;
    };

    auto gather = [&](const Par& P, int g) -> Gat {
        const char* base = fbb + g * 128 + cg * 16;
        Gat G;
        G.a = *(const s16x8*)(base + P.o0);
        G.b = *(const s16x8*)(base + P.o1);
        G.c = *(const s16x8*)(base + P.o2);
        G.d = *(const s16x8*)(base + P.o3);
        return G;
    };

    auto finish = [&](const Par& P, const Gat& G, int buf) {
        float r[8];
        #pragma unroll
        for (int j = 0; j < 8; ++j) {
            r[j] = P.w0 * bf2f((unsigned short)G.a[j])
                 + P.w1 * bf2f((unsigned short)G.b[j])
                 + P.w2 * bf2f((unsigned short)G.c[j])
                 + P.w3 * bf2f((unsigned short)G.d[j]);
        }
        unsigned int q0, q1, q2, q3;
        asm("v_cvt_pk_bf16_f32 %0, %1, %2" : "=v"(q0) : "v"(r[0]), "v"(r[1]));
        asm("v_cvt_pk_bf16_f32 %0, %1, %2" : "=v"(q1) : "v"(r[2]), "v"(r[3]));
        asm("v_cvt_pk_bf16_f32 %0, %1, %2" : "=v"(q2) : "v"(r[4]), "v"(r[5]));
        asm("v_cvt_pk_bf16_f32 %0, %1, %2" : "=v"(q3) : "v"(r[6]), "v"(r[7]));
        union { unsigned int q[4]; s16x8 v; } U;
        U.q[0] = q0; U.q[1] = q1; U.q[2] = q2; U.q[3] = q3;
        *(s16x8*)&vt[buf][px][cg * 8] = U.v;
    };

    // A-fragment register double-buffer: 4 frags per wave per step.
    s16x8 af00, af01, af10, af11;      // af[kk][mo]
    auto loadA = [&](int s) {
        const unsigned short* wfs = wfc + (size_t)s * 2048 * 8;
        af00 = *(const s16x8*)(wfs + ((size_t)( 0 + wv * 2 + 0) * 64 + lane) * 8);
        af01 = *(const s16x8*)(wfs + ((size_t)( 0 + wv * 2 + 1) * 64 + lane) * 8);
        af10 = *(const s16x8*)(wfs + ((size_t)(16 + wv * 2 + 0) * 64 + lane) * 8);
        af11 = *(const s16x8*)(wfs + ((size_t)(16 + wv * 2 + 1) * 64 + lane) * 8);
    };

    auto domfma = [&](int s) {
        s16x8 bfr[4];
        #pragma unroll
        for (int np = 0; np < 4; ++np)
            bfr[np] = *(const s16x8*)
                &vt[s & 1][np * 16 + (lane & 15)][(lane >> 4) * 8];          // kk=0
        #pragma unroll
        for (int np = 0; np < 4; ++np)
            acc[0][np] = __builtin_amdgcn_mfma_f32_16x16x32_bf16(af00, bfr[np],
                                                                 acc[0][np], 0, 0, 0);
        #pragma unroll
        for (int np = 0; np < 4; ++np)
            acc[1][np] = __builtin_amdgcn_mfma_f32_16x16x32_bf16(af01, bfr[np],
                                                                 acc[1][np], 0, 0, 0);
        #pragma unroll
        for (int np = 0; np < 4; ++np)
            bfr[np] = *(const s16x8*)
                &vt[s & 1][np * 16 + (lane & 15)][32 + (lane >> 4) * 8];     // kk=1
        #pragma unroll
        for (int np = 0; np < 4; ++np)
            acc[0][np] = __builtin_amdgcn_mfma_f32_16x16x32_bf16(af10, bfr[np],
                                                                 acc[0][np], 0, 0, 0);
        #pragma unroll
        for (int np = 0; np < 4; ++np)
            acc[1][np] = __builtin_amdgcn_mfma_f32_16x16x32_bf16(af11, bfr[np],
                                                                 acc[1][np], 0, 0, 0);
    };

    // ---- software pipeline ----
    loadA(0);
    Par pc = ldpar(0);
    Par pn = ldpar(1);
    Gat gc = gather(pc, 0);
    finish(pc, gc, 0);                  // vt[0]

    for (int s = 0; s < 36; ++s) {
        Gat gn;
        Par p2 = pn;
        bool hasn = (s + 1 < 36);
        if (hasn)        gn = gather(pn, (s + 1) & 3);   // in flight across barrier
        if (s + 2 < 36)  p2 = ldpar(s + 2);              // LDS read, drained below
        asm volatile("s_waitcnt lgkmcnt(0)" ::: "memory"); // LDS writes visible
        __builtin_amdgcn_s_barrier();                      // vmcnt NOT drained
        domfma(s);                       // pure LDS + MFMA (af prefetched)
        if (hasn) {
            loadA(s + 1);                // lands during finish + next gather phase
            finish(pn, gn, (s + 1) & 1);
        }
        pn = p2;
    }

    // epilogue: C/D layout col = lane&15 (pixel), row = (lane>>4)*4 + reg (o)
    float* ob = out + (size_t)conv * (NB * 256 * HW) + (size_t)b * 256 * HW;
    #pragma unroll
    for (int mo = 0; mo < 2; ++mo)
        #pragma unroll
        for (int np = 0; np < 4; ++np)
            #pragma unroll
            for (int r = 0; r < 4; ++r) {
                int o = wv * 32 + mo * 16 + (lane >> 4) * 4 + r;
                int p = p0 + np * 16 + (lane & 15);
                float v = acc[mo][np][r];
                ob[(size_t)o * HW + p] = v > 0.f ? v : 0.f;
            }
}

// ---------------------------------------------------------------------------
// ws layout (bytes):
//   [0,        8388608)  fbuf  : 4*4096*256 bf16 NHWC
//   [8388608, 10747904)  wfrag : 2*73728*8 bf16
// requires ws_size >= 10747904
// ---------------------------------------------------------------------------
extern "C" void kernel_launch(void* const* d_in, const int* in_sizes, int n_in,
                              void* d_out, int out_size, void* d_ws, size_t ws_size,
                              hipStream_t stream) {
    (void)in_sizes; (void)n_in; (void)out_size; (void)ws_size;
    const float* reg_feat = (const float*)d_in[0];
    const float* cls_feat = (const float*)d_in[1];
    const float* pred     = (const float*)d_in[2];
    const float* w_off    = (const float*)d_in[3];
    const float* w_reg    = (const float*)d_in[4];
    const float* w_cls    = (const float*)d_in[5];
    float* out = (float*)d_out;
    char* ws = (char*)d_ws;
    unsigned short* fbuf  = (unsigned short*)ws;
    unsigned short* wfrag = (unsigned short*)(ws + 8388608);

    k_prep<<<1600, 256, 0, stream>>>(reg_feat, cls_feat, w_reg, w_cls, fbuf, wfrag);
    k_main<<< 256, 512, 0, stream>>>(pred, w_off, fbuf, wfrag, out);
}

// Round 7
// 54.871 us; speedup vs baseline: 1.1681x; 1.1681x over previous
//
#include <hip/hip_runtime.h>
#include <hip/hip_bf16.h>
#include <stdint.h>

// Problem constants (fixed by setup_inputs): B=2, C=256, H=W=64, dg=4, K=3x3.
#define HW   4096
#define NB   2

typedef float f32x4 __attribute__((ext_vector_type(4)));
typedef short s16x8 __attribute__((ext_vector_type(8)));

__device__ __forceinline__ unsigned short f2bf(float f) {
    // round-to-nearest-even f32 -> bf16
    union { float f; unsigned int u; } v; v.f = f;
    unsigned int u = v.u;
    unsigned int r = (u + 0x7FFFu + ((u >> 16) & 1u)) >> 16;
    return (unsigned short)r;
}

__device__ __forceinline__ float bf2f(unsigned short u) {
    union { unsigned int u; float f; } v; v.u = ((unsigned int)u) << 16;
    return v.f;
}

// ---------------------------------------------------------------------------
// K_prep: three independent prep stages in ONE dispatch (R5-proven).
//   blocks [0,1152)     : offset 1x1 conv + bilinear setup (wbuf/ibuf)
//   blocks [1152,2176)  : NCHW f32 -> NHWC bf16 transpose  (fbuf)
//   blocks [2176,2752)  : weights -> bf16 MFMA A-frag order (wfrag)
// ---------------------------------------------------------------------------
__global__ void __launch_bounds__(256)
k_prep(const float* __restrict__ pred, const float* __restrict__ wo,
       const float* __restrict__ regf, const float* __restrict__ clsf,
       const float* __restrict__ wr,   const float* __restrict__ wc,
       float4* __restrict__ wbuf, int4* __restrict__ ibuf,
       unsigned short* __restrict__ fbuf, unsigned short* __restrict__ wfrag) {
    int bb = blockIdx.x;
    if (bb < 1152) {
        // ---- params: loc = ((b*9+k)*4+g)*4096 + p ----
        int loc = bb * 256 + threadIdx.x;
        int p  = loc & 4095;
        int g  = (loc >> 12) & 3;
        int bk = loc >> 14;
        int b  = bk / 9;
        int k  = bk - b * 9;
        int rowy = ((g * 9 + k) * 2) * 34;
        float oy = 0.f, ox = 0.f;
        const float* pb = pred + (size_t)b * 34 * HW + p;
        #pragma unroll
        for (int c = 0; c < 34; ++c) {
            float pv = pb[c * HW];
            oy += wo[rowy + c]      * pv;
            ox += wo[rowy + 34 + c] * pv;
        }
        int h = p >> 6, w = p & 63;
        int ky = k / 3, kx = k - ky * 3;
        float py = oy + (float)(h + ky - 1);
        float px = ox + (float)(w + kx - 1);
        float fy0 = floorf(py), fx0 = floorf(px);
        int y0 = (int)fy0, x0 = (int)fx0;
        float fy = py - fy0, fx = px - fx0;
        float wy0 = 1.f - fy, wy1 = fy, wx0 = 1.f - fx, wx1 = fx;
        if (!(y0 >= 0  && y0 <= 63)) wy0 = 0.f;
        if (!(y0 >= -1 && y0 <= 62)) wy1 = 0.f;
        if (!(x0 >= 0  && x0 <= 63)) wx0 = 0.f;
        if (!(x0 >= -1 && x0 <= 62)) wx1 = 0.f;
        int cy0 = min(max(y0, 0), 63),     cy1 = min(max(y0 + 1, 0), 63);
        int cx0 = min(max(x0, 0), 63),     cx1 = min(max(x0 + 1, 0), 63);
        wbuf[loc] = make_float4(wy0 * wx0, wy0 * wx1, wy1 * wx0, wy1 * wx1);
        ibuf[loc] = make_int4((cy0 * 64 + cx0) << 9, (cy0 * 64 + cx1) << 9,
                              (cy1 * 64 + cx0) << 9, (cy1 * 64 + cx1) << 9);
    } else if (bb < 2176) {
        // ---- NCHW f32 -> NHWC bf16 ----
        __shared__ float tile[64][65];
        int bid = bb - 1152;
        int pt = bid & 63;
        int cb = (bid >> 6) & 3;
        int b  = (bid >> 8) & 1;
        int cv = bid >> 9;
        const float* src = cv ? clsf : regf;
        int t = threadIdx.x;
        int pl = t & 63, q = t >> 6;
        #pragma unroll
        for (int i = 0; i < 16; ++i) {
            int cl = q + i * 4;
            tile[cl][pl] = src[((size_t)(b * 256 + cb * 64 + cl)) * HW + pt * 64 + pl];
        }
        __syncthreads();
        int cpair = t & 31, prow = t >> 5;
        #pragma unroll
        for (int i = 0; i < 8; ++i) {
            int p = i * 8 + prow;
            unsigned int u0 = f2bf(tile[cpair * 2][p]);
            unsigned int u1 = f2bf(tile[cpair * 2 + 1][p]);
            *(unsigned int*)&fbuf[((size_t)((cv * 2 + b) * HW + pt * 64 + p)) * 256
                                  + cb * 64 + cpair * 2] = u0 | (u1 << 16);
        }
    } else {
        // ---- weights -> A-frag: L = conv*73728 + ((s*2+kk)*16+ot)*64+lane ----
        int L = (bb - 2176) * 256 + threadIdx.x;
        int conv = L / 73728;
        int r = L - conv * 73728;
        int lane = r & 63;
        int ot = (r >> 6) & 15;
        int kk = (r >> 10) & 1;
        int s  = r >> 11;
        int k = s >> 2, g = s & 3;
        int o  = ot * 16 + (lane & 15);
        int cb = kk * 32 + (lane >> 4) * 8;
        const float* w = conv ? wc : wr;
        s16x8 v;
        #pragma unroll
        for (int j = 0; j < 8; ++j) {
            int c = cb + j;
            v[j] = (short)f2bf(w[((size_t)o * 256 + g * 64 + c) * 9 + k]);
        }
        *(s16x8*)(wfrag + (size_t)L * 8) = v;
    }
}

// ---------------------------------------------------------------------------
// K_main: producer/consumer wave-specialized implicit GEMM.
// Block = (conv,b,64-px tile) x 256 Cout; 256 blocks x 512 threads (8 waves).
//   waves 0-3 (producers): build sampled V tile (gather+lerp+pack) into
//     vt[(s+1)&1]; params+gathers prefetched 1-2 steps ahead (fly across
//     barriers via vmcnt).  Each thread: 2 granules (px0, px0+32) x 8 ch.
//   waves 4-7 (consumers): 64 Cout x 64 px each; 32 MFMA/step from vt[s&1];
//     A-frags register-double-buffered from global.
// ONE barrier per step; producer and consumer work overlaps across waves
// (MFMA + VALU + LDS + TA pipes run concurrently, m114).
// ---------------------------------------------------------------------------
__global__ void __launch_bounds__(512, 2)
k_main(const float4* __restrict__ wbuf, const int4* __restrict__ ibuf,
       const unsigned short* __restrict__ fbuf, const unsigned short* __restrict__ wfrag,
       float* __restrict__ out) {
    __shared__ __align__(16) unsigned short vt[2][64][72];   // 64 px x 64 ch + pad

    int bid0 = blockIdx.x;
    int bid = (bid0 & 7) * 32 + (bid0 >> 3);       // XCD-contiguous swizzle (256%8==0)
    int conv = bid >> 7;
    int b    = (bid >> 6) & 1;
    int pt   = bid & 63;
    int p0   = pt * 64;

    int tid  = threadIdx.x;
    int lane = tid & 63;
    int wv   = tid >> 6;

    const char* fbb = (const char*)(fbuf + (size_t)(conv * 2 + b) * HW * 256);
    const unsigned short* wfc = wfrag + (size_t)conv * 73728 * 8;

    if (wv < 4) {
        // =================== PRODUCER (waves 0-3) ===================
        int px0 = tid >> 3;                        // 0..31 ; also handles px0+32
        int cg  = tid & 7;                         // channel granule (8 ch)

        struct Par { float w0, w1, w2, w3; int o0, o1, o2, o3; };
        struct Gat { s16x8 a, b, c, d; };

        auto ldpar = [&](int s, int dpx) -> Par {
            int k = s >> 2, g = s & 3;
            int pidx = ((b * 9 + k) * 4 + g) * HW + p0 + px0 + dpx;
            float4 w4 = wbuf[pidx];
            int4   io = ibuf[pidx];
            Par P;
            P.w0 = w4.x; P.w1 = w4.y; P.w2 = w4.z; P.w3 = w4.w;
            P.o0 = io.x; P.o1 = io.y; P.o2 = io.z; P.o3 = io.w;
            return P;
        };

        auto gather = [&](const Par& P, int g) -> Gat {
            const char* base = fbb + g * 128 + cg * 16;
            Gat G;
            G.a = *(const s16x8*)(base + P.o0);
            G.b = *(const s16x8*)(base + P.o1);
            G.c = *(const s16x8*)(base + P.o2);
            G.d = *(const s16x8*)(base + P.o3);
            return G;
        };

        auto finish = [&](const Par& P, const Gat& G, int px, int buf) {
            float r[8];
            #pragma unroll
            for (int j = 0; j < 8; ++j) {
                r[j] = P.w0 * bf2f((unsigned short)G.a[j])
                     + P.w1 * bf2f((unsigned short)G.b[j])
                     + P.w2 * bf2f((unsigned short)G.c[j])
                     + P.w3 * bf2f((unsigned short)G.d[j]);
            }
            s16x8 pk;
            #pragma unroll
            for (int j = 0; j < 8; ++j) pk[j] = (short)f2bf(r[j]);
            *(s16x8*)&vt[buf][px][cg * 8] = pk;
        };

        // prologue: build vt[0]; prefetch params/gathers for step 1
        Par pa = ldpar(0, 0),  pb = ldpar(0, 32);   // step 0
        Par na = ldpar(1, 0),  nb = ldpar(1, 32);   // step 1
        Gat ga = gather(pa, 0), gb = gather(pb, 0);
        finish(pa, ga, px0, 0);
        finish(pb, gb, px0 + 32, 0);
        Par fa = ldpar(2, 0),  fbp = ldpar(2, 32);  // step 2
        ga = gather(na, 1); gb = gather(nb, 1);     // step-1 gathers in flight
        asm volatile("s_waitcnt lgkmcnt(0)" ::: "memory");
        __builtin_amdgcn_s_barrier();               // barrier #0

        for (int i = 1; i < 36; ++i) {
            // issue gathers for step i+1 (fly across barrier #i)
            Gat g2a, g2b;
            if (i < 35) { g2a = gather(fa, (i + 1) & 3); g2b = gather(fbp, (i + 1) & 3); }
            Par p3a = fa, p3b = fbp;
            if (i < 34) { p3a = ldpar(i + 2, 0); p3b = ldpar(i + 2, 32); }
            // build vt[i&1] for consumer step i (gathers issued at i-1, landed)
            finish(na, ga, px0, i & 1);
            finish(nb, gb, px0 + 32, i & 1);
            na = fa; nb = fbp; fa = p3a; fbp = p3b;
            ga = g2a; gb = g2b;
            asm volatile("s_waitcnt lgkmcnt(0)" ::: "memory"); // vt writes visible
            __builtin_amdgcn_s_barrier();            // barrier #i (vmcnt in flight)
        }
        // producers done (35 finishes after prologue = tiles 1..35)
    } else {
        // =================== CONSUMER (waves 4-7) ===================
        int cw = wv - 4;                            // Cout slice: cw*64 + [0,64)

        f32x4 acc[4][4];
        #pragma unroll
        for (int i = 0; i < 4; ++i)
            #pragma unroll
            for (int j = 0; j < 4; ++j)
                acc[i][j] = (f32x4){0.f, 0.f, 0.f, 0.f};

        s16x8 af[2][4];                             // af[kk][mo], double-buffered
        auto loadA = [&](int s) {
            const unsigned short* wfs = wfc + (size_t)s * 2048 * 8;
            #pragma unroll
            for (int kk = 0; kk < 2; ++kk)
                #pragma unroll
                for (int mo = 0; mo < 4; ++mo)
                    af[kk][mo] = *(const s16x8*)
                        (wfs + ((size_t)(kk * 16 + cw * 4 + mo) * 64 + lane) * 8);
        };

        loadA(0);
        __builtin_amdgcn_s_barrier();               // barrier #0

        for (int s = 0; s < 36; ++s) {
            #pragma unroll
            for (int kk = 0; kk < 2; ++kk) {
                s16x8 bfr[4];
                #pragma unroll
                for (int np = 0; np < 4; ++np)
                    bfr[np] = *(const s16x8*)
                        &vt[s & 1][np * 16 + (lane & 15)][kk * 32 + (lane >> 4) * 8];
                #pragma unroll
                for (int mo = 0; mo < 4; ++mo)
                    #pragma unroll
                    for (int np = 0; np < 4; ++np)
                        acc[mo][np] = __builtin_amdgcn_mfma_f32_16x16x32_bf16(
                            af[kk][mo], bfr[np], acc[mo][np], 0, 0, 0);
            }
            if (s < 35) {
                loadA(s + 1);                       // overwrites af after last use
                __builtin_amdgcn_s_barrier();       // barrier #s+1
            }
        }

        // epilogue: C/D layout col = lane&15 (pixel), row = (lane>>4)*4 + reg
        float* ob = out + (size_t)conv * (NB * 256 * HW) + (size_t)b * 256 * HW;
        #pragma unroll
        for (int mo = 0; mo < 4; ++mo)
            #pragma unroll
            for (int np = 0; np < 4; ++np)
                #pragma unroll
                for (int r = 0; r < 4; ++r) {
                    int o = cw * 64 + mo * 16 + (lane >> 4) * 4 + r;
                    int p = p0 + np * 16 + (lane & 15);
                    float v = acc[mo][np][r];
                    ob[(size_t)o * HW + p] = v > 0.f ? v : 0.f;
                }
    }
}

// ---------------------------------------------------------------------------
// ws layout (bytes):
//   [0,        4718592)  wbuf  : 294912 float4
//   [4718592,  9437184)  ibuf  : 294912 int4
//   [9437184, 17825792)  fbuf  : 4*4096*256 bf16 NHWC
//   [17825792,20185088)  wfrag : 2*73728*8 bf16
// requires ws_size >= 20185088
// ---------------------------------------------------------------------------
extern "C" void kernel_launch(void* const* d_in, const int* in_sizes, int n_in,
                              void* d_out, int out_size, void* d_ws, size_t ws_size,
                              hipStream_t stream) {
    (void)in_sizes; (void)n_in; (void)out_size; (void)ws_size;
    const float* reg_feat = (const float*)d_in[0];
    const float* cls_feat = (const float*)d_in[1];
    const float* pred     = (const float*)d_in[2];
    const float* w_off    = (const float*)d_in[3];
    const float* w_reg    = (const float*)d_in[4];
    const float* w_cls    = (const float*)d_in[5];
    float* out = (float*)d_out;
    char* ws = (char*)d_ws;
    float4*         wbuf  = (float4*)ws;
    int4*           ibuf  = (int4*)(ws + 4718592);
    unsigned short* fbuf  = (unsigned short*)(ws + 9437184);
    unsigned short* wfrag = (unsigned short*)(ws + 17825792);

    k_prep<<<2752, 256, 0, stream>>>(pred, w_off, reg_feat, cls_feat, w_reg, w_cls,
                                     wbuf, ibuf, fbuf, wfrag);
    k_main<<< 256, 512, 0, stream>>>(wbuf, ibuf, fbuf, wfrag, out);
}